// Round 11
// baseline (34.335 us; speedup 1.0000x reference)
//
#include <hip/hip_runtime.h>

// 5x5 lower-median filter, reflect padding, fp32 in/out, x: [8,3,512,512]
// R11: R8 kernel (best: asm packed-fp16, 8x2 tiles, aligned loads) with an
// XCD-aware block remap: hardware round-robins blockIdx%8 across the 8 XCDs,
// so give XCD x the contiguous work-range [x*195, (x+1)*195) = 3 whole
// channels in y-ascending order -> vertical halo rows hit the same XCD L2.
static constexpr int H = 512, W = 512;
static constexpr int QX_I = 62;                      // interior 8x2 tiles per row-pair
static constexpr int TILES_I = QX_I * 254;           // 15748
static constexpr int IB = (TILES_I + 255) / 256;     // 62 interior blocks/img
static constexpr int EDGE_N = 2 * 256 + 2 * QX_I;    // 636 edge tiles/img
static constexpr int EB = (EDGE_N + 255) / 256;      // 3 edge blocks/img
static constexpr int BPC = IB + EB;                  // 65 blocks per channel
static constexpr int NCH = 24;                       // 8*3 channels
static constexpr int NBLK = BPC * NCH;               // 1560 = 8 * 195
static constexpr int PER_XCD = NBLK / 8;             // 195

typedef __fp16 h2 __attribute__((ext_vector_type(2)));
typedef float f4 __attribute__((ext_vector_type(4), aligned(16)));
typedef float f4a __attribute__((ext_vector_type(4), aligned(16)));

// packed single-instruction comparators (non-volatile asm: CSE/schedulable)
__device__ __forceinline__ h2 PMN(h2 a, h2 b) {
    h2 d; asm("v_pk_min_f16 %0, %1, %2" : "=v"(d) : "v"(a), "v"(b)); return d;
}
__device__ __forceinline__ h2 PMX(h2 a, h2 b) {
    h2 d; asm("v_pk_max_f16 %0, %1, %2" : "=v"(d) : "v"(a), "v"(b)); return d;
}
__device__ __forceinline__ void PCE(h2& a, h2& b) {
    h2 lo = PMN(a, b), hi = PMX(a, b); a = lo; b = hi;
}
// med3(t,u,x) given u <= t  ==  max(u, min(t,x))
__device__ __forceinline__ h2 IMD(h2 t, h2 u, h2 x) { return PMX(u, PMN(t, x)); }

// Lower median (rank 12 of 25) for pack-window B: lo half = window at cols
// B..B+4, hi half = window at cols B+4..B+8 of column-sorted packs S[5][8].
template<int B>
__device__ __forceinline__ h2 med25p(const h2 S[5][8]) {
    // rowA (col minima): keep top2, u<=t
    h2 u = PMN(S[0][B], S[0][B+1]), t = PMX(S[0][B], S[0][B+1]);
    u = IMD(t, u, S[0][B+2]); t = PMX(t, S[0][B+2]);
    u = IMD(t, u, S[0][B+3]); t = PMX(t, S[0][B+3]);
    u = IMD(t, u, S[0][B+4]); t = PMX(t, S[0][B+4]);
    h2 A0 = u, A1 = t;
    // rowB: keep top3 sorted l<=m<=h
    h2 mn1 = PMN(S[1][B], S[1][B+1]), mx1 = PMX(S[1][B], S[1][B+1]);
    h2 l = PMN(mn1, S[1][B+2]), h = PMX(mx1, S[1][B+2]);
    h2 m = PMX(mn1, PMN(mx1, S[1][B+2]));
    { h2 x = S[1][B+3]; h2 nl = IMD(m,l,x), nm = IMD(h,m,x), nh = PMX(h,x); l=nl; m=nm; h=nh; }
    { h2 x = S[1][B+4]; h2 nl = IMD(m,l,x), nm = IMD(h,m,x), nh = PMX(h,x); l=nl; m=nm; h=nh; }
    h2 B0 = l, B1 = m, B2 = h;
    // rowC (col medians): keep middle3
    h2 mn2 = PMN(S[2][B], S[2][B+1]), mx2 = PMX(S[2][B], S[2][B+1]);
    h2 l2 = PMN(mn2, S[2][B+2]), hh = PMX(mx2, S[2][B+2]);
    h2 m2 = PMX(mn2, PMN(mx2, S[2][B+2]));
    h2 d4 = S[2][B+3];
    h2 s0 = PMN(l2, d4), s1 = IMD(m2, l2, d4), s2 = IMD(hh, m2, d4), s3 = PMX(hh, d4);
    h2 e4 = S[2][B+4];
    h2 C0 = IMD(s1, s0, e4), C1 = IMD(s2, s1, e4), C2 = IMD(s3, s2, e4);
    // rowD: keep bottom3
    h2 mn3 = PMN(S[3][B], S[3][B+1]), mx3 = PMX(S[3][B], S[3][B+1]);
    h2 l3 = PMN(mn3, S[3][B+2]), h3 = PMX(mx3, S[3][B+2]);
    h2 m3 = PMX(mn3, PMN(mx3, S[3][B+2]));
    { h2 x = S[3][B+3]; h2 nl = PMN(l3,x), nm = IMD(m3,l3,x), nh = IMD(h3,m3,x); l3=nl; m3=nm; h3=nh; }
    { h2 x = S[3][B+4]; h2 nl = PMN(l3,x), nm = IMD(m3,l3,x), nh = IMD(h3,m3,x); l3=nl; m3=nm; h3=nh; }
    h2 D0 = l3, D1 = m3, D2 = h3;
    // rowE (col maxima): keep bottom2, p<=q
    h2 p = PMN(S[4][B], S[4][B+1]), q = PMX(S[4][B], S[4][B+1]);
    q = IMD(q, p, S[4][B+2]); p = PMN(p, S[4][B+2]);
    q = IMD(q, p, S[4][B+3]); p = PMN(p, S[4][B+3]);
    q = IMD(q, p, S[4][B+4]); p = PMN(p, S[4][B+4]);
    h2 E0 = p, E1 = q;

    // G4 = merge(A2, E2): (A0,E0,A1,E1)
    PCE(A0, E0); PCE(A1, E1); PCE(E0, A1);
    h2 G0 = A0, G1 = E0, G2 = A1, G3 = E1;
    // F6 = merge(B3, C3): odd-even merge -> (B0,B1,C0,C1,B2,C2)
    PCE(B0, C0); PCE(B2, C2); PCE(C0, B2);
    PCE(B1, C1);
    PCE(B1, C0); PCE(C1, B2);
    h2 F0 = B0, F1 = B1, F2 = C0, F3 = C1, F4 = B2, F5 = C2;
    // H7 = merge(D3, G4): odd-even merge -> (D0,D1,G0,G1,D2,G3,G2)
    PCE(D0, G0); PCE(D2, G2); PCE(G0, D2);
    PCE(D1, G1); PCE(G1, G3);
    PCE(D1, G0); PCE(G1, D2); PCE(G3, G2);
    h2 H0 = D0, H1 = D1, H2 = G0, H3 = G1, H4 = D2, H5 = G3, H6 = G2;
    // median of 13 = 7th of F(6) U H(7) = min over i+j=7 of max(F[i-1],H[j-1])
    h2 r = PMN(H6, PMX(F0, H5));
    r = PMN(r, PMX(F1, H4));
    r = PMN(r, PMX(F2, H3));
    r = PMN(r, PMX(F3, H2));
    r = PMN(r, PMX(F4, H1));
    r = PMN(r, PMX(F5, H0));
    return r;
}

// one output row: insert edge row xr into sorted-4 columns, run 4 pack-windows
__device__ __forceinline__ void do_row(const h2* q0, const h2* q1, const h2* q2, const h2* q3,
                                       const h2* xr, float* outp) {
    h2 T[5][8];
    #pragma unroll
    for (int k = 0; k < 8; ++k) {
        h2 x = xr[k];
        T[0][k] = PMN(q0[k], x);
        T[1][k] = IMD(q1[k], q0[k], x);
        T[2][k] = IMD(q2[k], q1[k], x);
        T[3][k] = IMD(q3[k], q2[k], x);
        T[4][k] = PMX(q3[k], x);
    }
    h2 r0 = med25p<0>(T), r1 = med25p<1>(T), r2 = med25p<2>(T), r3 = med25p<3>(T);
    f4a lo, hi;
    lo.x = (float)r0.x; lo.y = (float)r1.x; lo.z = (float)r2.x; lo.w = (float)r3.x;
    hi.x = (float)r0.y; hi.y = (float)r1.y; hi.z = (float)r2.y; hi.w = (float)r3.y;
    *(f4a*)outp = lo;
    *(f4a*)(outp + 4) = hi;
}

// aligned row load (base = row + x0 - 4, 16B-aligned) + pack to 8 h2
// pack[k] = (col x0-2+k, col x0+2+k) = (f[k+2], f[k+6]) of the 16 floats
__device__ __forceinline__ void loadrow_pack(const float* p, h2 out[8]) {
    f4 A = *(const f4*)p;
    f4 Bv = *(const f4*)(p + 4);
    f4 C = *(const f4*)(p + 8);
    f4 D = *(const f4*)(p + 12);
    out[0] = __builtin_amdgcn_cvt_pkrtz(A.z,  Bv.z);
    out[1] = __builtin_amdgcn_cvt_pkrtz(A.w,  Bv.w);
    out[2] = __builtin_amdgcn_cvt_pkrtz(Bv.x, C.x);
    out[3] = __builtin_amdgcn_cvt_pkrtz(Bv.y, C.y);
    out[4] = __builtin_amdgcn_cvt_pkrtz(Bv.z, C.z);
    out[5] = __builtin_amdgcn_cvt_pkrtz(Bv.w, C.w);
    out[6] = __builtin_amdgcn_cvt_pkrtz(C.x,  D.x);
    out[7] = __builtin_amdgcn_cvt_pkrtz(C.y,  D.y);
}

__device__ __forceinline__ int refl(int z, int n) {
    z = (z < 0) ? -z : z;
    return (z >= n) ? 2 * n - 2 - z : z;
}

__global__ __launch_bounds__(256, 4) void median5x5_kernel(const float* __restrict__ in,
                                                           float* __restrict__ out) {
    // XCD-aware remap: hardware XCD = blockIdx.x % 8; give each XCD a
    // contiguous work range (3 channels, y-ascending) for L2 halo reuse.
    int L   = blockIdx.x;            // 0..1559
    int xcd = L & 7;
    int idx = L >> 3;                // 0..194
    int wid = xcd * PER_XCD + idx;   // contiguous per XCD
    int bc  = wid / BPC;             // channel 0..23
    int bx  = wid - bc * BPC;        // 0..64 within channel

    const float* __restrict__ img  = in  + (size_t)bc * (H * W);
    float*       __restrict__ outc = out + (size_t)bc * (H * W);

    int x0, y0;
    h2 m1[8], m2[8], m3[8], m4[8];    // shared mid rows (y0-1..y0+2), packed
    h2 e0[8], e5[8];                  // edge rows (y0-2, y0+3), packed

    if (bx < IB) {
        int i = bx * 256 + threadIdx.x;
        if (i >= TILES_I) return;
        int r  = i / QX_I;
        int qx = i - r * QX_I;
        x0 = 8 * (qx + 1);           // 8..496
        y0 = 2 * (r + 1);            // 2..508
        const float* base = img + (y0 - 2) * W + (x0 - 4);   // 16B aligned
        loadrow_pack(base + 1 * W, m1);
        loadrow_pack(base + 2 * W, m2);
        loadrow_pack(base + 3 * W, m3);
        loadrow_pack(base + 4 * W, m4);
        loadrow_pack(base + 0 * W, e0);
        loadrow_pack(base + 5 * W, e5);
    } else {
        int j = (bx - IB) * 256 + threadIdx.x;
        if (j >= EDGE_N) return;
        int qx, r;
        if (j < 512) { qx = (j & 1) ? 63 : 0; r = j >> 1; }
        else {
            int k2 = j - 512;
            if (k2 < QX_I) { r = 0;   qx = k2 + 1; }
            else           { r = 255; qx = k2 - (QX_I - 1); }
        }
        x0 = 8 * qx; y0 = 2 * r;
        int ry[6], rx[12];
        #pragma unroll
        for (int i2 = 0; i2 < 6; ++i2) ry[i2] = refl(y0 - 2 + i2, H);
        #pragma unroll
        for (int k = 0; k < 12; ++k) rx[k] = refl(x0 - 2 + k, W);
        h2* rows[6] = { e0, m1, m2, m3, m4, e5 };
        #pragma unroll
        for (int rr = 0; rr < 6; ++rr) {
            float tmp[12];
            #pragma unroll
            for (int k = 0; k < 12; ++k) tmp[k] = img[ry[rr] * W + rx[k]];
            #pragma unroll
            for (int k = 0; k < 8; ++k)
                rows[rr][k] = __builtin_amdgcn_cvt_pkrtz(tmp[k], tmp[k + 4]);
        }
    }

    // sorted-4 of shared mid rows, per packed column (mid rows die here)
    h2 q0[8], q1[8], q2[8], q3[8];
    #pragma unroll
    for (int k = 0; k < 8; ++k) {
        h2 a = m1[k], b = m2[k], c = m3[k], d = m4[k];
        h2 mn = PMN(a, b), mx = PMX(a, b);
        h2 l = PMN(mn, c), hh = PMX(mx, c);
        h2 m = PMX(mn, PMN(mx, c));
        q0[k] = PMN(l, d); q1[k] = IMD(m, l, d); q2[k] = IMD(hh, m, d); q3[k] = PMX(hh, d);
    }
    do_row(q0, q1, q2, q3, e0, outc + y0 * W + x0);
    do_row(q0, q1, q2, q3, e5, outc + (y0 + 1) * W + x0);
}

extern "C" void kernel_launch(void* const* d_in, const int* in_sizes, int n_in,
                              void* d_out, int out_size, void* d_ws, size_t ws_size,
                              hipStream_t stream) {
    const float* x = (const float*)d_in[0];
    float* out = (float*)d_out;
    dim3 grid(NBLK, 1, 1);
    median5x5_kernel<<<grid, 256, 0, stream>>>(x, out);
}

// Round 13
// 25.578 us; speedup vs baseline: 1.3423x; 1.3423x over previous
//
#include <hip/hip_runtime.h>

// 5x5 lower-median filter, reflect padding, fp32 in/out, x: [8,3,512,512]
// R13: R12 with the rowC (3,2)-merge bug fixed (proper 5-CE Batcher merge).
// van-Herk shared prefix/suffix scans across the 4 window positions.
static constexpr int H = 512, W = 512;
static constexpr int QX_I = 62;                      // interior 8x2 tiles per row-pair
static constexpr int TILES_I = QX_I * 254;           // 15748
static constexpr int IB = (TILES_I + 255) / 256;     // 62 interior blocks/img
static constexpr int EDGE_N = 2 * 256 + 2 * QX_I;    // 636 edge tiles/img
static constexpr int EB = (EDGE_N + 255) / 256;      // 3 edge blocks/img

typedef __fp16 h2 __attribute__((ext_vector_type(2)));
typedef float f4u __attribute__((ext_vector_type(4), aligned(4)));
typedef float f4a __attribute__((ext_vector_type(4), aligned(16)));

__device__ __forceinline__ h2 PMN(h2 a, h2 b) {
    h2 d; asm("v_pk_min_f16 %0, %1, %2" : "=v"(d) : "v"(a), "v"(b)); return d;
}
__device__ __forceinline__ h2 PMX(h2 a, h2 b) {
    h2 d; asm("v_pk_max_f16 %0, %1, %2" : "=v"(d) : "v"(a), "v"(b)); return d;
}
__device__ __forceinline__ void PCE(h2& a, h2& b) {
    h2 lo = PMN(a, b), hi = PMX(a, b); a = lo; b = hi;
}
// med3(t,u,x) given u <= t  ==  max(u, min(t,x))
__device__ __forceinline__ h2 IMD(h2 t, h2 u, h2 x) { return PMX(u, PMN(t, x)); }

// rank-7-of-13 from sorted runs A2,B3,C3,D3,E2 (ascending each):
// G=merge(A,E); F=merge(B,C); H=merge(D,G); median = min over i+j=7 of
// max(F[i-1],H[j-1]). (Verified R4-R8.)
__device__ __forceinline__ h2 med13(h2 A0, h2 A1, h2 B0, h2 B1, h2 B2,
                                    h2 C0, h2 C1, h2 C2, h2 D0, h2 D1, h2 D2,
                                    h2 E0, h2 E1) {
    // G4 = merge(A2, E2): (A0,E0,A1,E1)
    PCE(A0, E0); PCE(A1, E1); PCE(E0, A1);
    h2 G0 = A0, G1 = E0, G2 = A1, G3 = E1;
    // F6 = merge(B3, C3): odd-even -> (B0,B1,C0,C1,B2,C2)
    PCE(B0, C0); PCE(B2, C2); PCE(C0, B2);
    PCE(B1, C1);
    PCE(B1, C0); PCE(C1, B2);
    h2 F0 = B0, F1 = B1, F2 = C0, F3 = C1, F4 = B2, F5 = C2;
    // H7 = merge(D3, G4): odd-even -> (D0,D1,G0,G1,D2,G3,G2)
    PCE(D0, G0); PCE(D2, G2); PCE(G0, D2);
    PCE(D1, G1); PCE(G1, G3);
    PCE(D1, G0); PCE(G1, D2); PCE(G3, G2);
    h2 H0 = D0, H1 = D1, H2 = G0, H3 = G1, H4 = D2, H5 = G3, H6 = G2;
    h2 r = PMN(H6, PMX(F0, H5));
    r = PMN(r, PMX(F1, H4));
    r = PMN(r, PMX(F2, H3));
    r = PMN(r, PMX(F3, H2));
    r = PMN(r, PMX(F4, H1));
    r = PMN(r, PMX(F5, H0));
    return r;
}

// one output row: T = sorted-5 columns (insert xr into sorted-4 q);
// shared scans produce the 5 exclusion runs for all 4 windows; med13 each.
__device__ __forceinline__ void do_row(const h2* q0, const h2* q1, const h2* q2, const h2* q3,
                                       const h2* xr, float* outp) {
    h2 T0[8], T1[8], T2[8], T3[8], T4[8];
    #pragma unroll
    for (int k = 0; k < 8; ++k) {
        h2 x = xr[k];
        T0[k] = PMN(q0[k], x);
        T1[k] = IMD(q1[k], q0[k], x);
        T2[k] = IMD(q2[k], q1[k], x);
        T3[k] = IMD(q3[k], q2[k], x);
        T4[k] = PMX(q3[k], x);
    }
    // ---- rowA: top2 (ascending) of T0 over window B..B+4 ----
    h2 A0w[4], A1w[4];
    {
        h2 au3 = PMN(T0[3], T0[4]), at3 = PMX(T0[3], T0[4]);
        h2 au2 = IMD(at3, au3, T0[2]), at2 = PMX(at3, T0[2]);
        h2 au1 = IMD(at2, au2, T0[1]), at1 = PMX(at2, T0[1]);
        h2 au0 = IMD(at1, au1, T0[0]), at0 = PMX(at1, T0[0]);
        h2 pu6 = PMN(T0[5], T0[6]), pt6 = PMX(T0[5], T0[6]);
        h2 pu7 = IMD(pt6, pu6, T0[7]), pt7 = PMX(pt6, T0[7]);
        A0w[0] = au0; A1w[0] = at0;
        A0w[1] = IMD(at1, au1, T0[5]); A1w[1] = PMX(at1, T0[5]);
        A1w[2] = PMX(at2, pt6); A0w[2] = PMX(PMN(at2, pt6), PMX(au2, pu6));
        A1w[3] = PMX(at3, pt7); A0w[3] = PMX(PMN(at3, pt7), PMX(au3, pu7));
    }
    // ---- rowE: bottom2 (ascending) of T4 ----
    h2 E0w[4], E1w[4];
    {
        h2 bu3 = PMN(T4[3], T4[4]), bt3 = PMX(T4[3], T4[4]);
        h2 bu2 = PMN(bu3, T4[2]), bt2 = PMN(bt3, PMX(bu3, T4[2]));
        h2 bu1 = PMN(bu2, T4[1]), bt1 = PMN(bt2, PMX(bu2, T4[1]));
        h2 bu0 = PMN(bu1, T4[0]), bt0 = PMN(bt1, PMX(bu1, T4[0]));
        h2 qu6 = PMN(T4[5], T4[6]), qt6 = PMX(T4[5], T4[6]);
        h2 qu7 = PMN(qu6, T4[7]), qt7 = PMN(qt6, PMX(qu6, T4[7]));
        E0w[0] = bu0; E1w[0] = bt0;
        E0w[1] = PMN(bu1, T4[5]); E1w[1] = PMN(bt1, PMX(bu1, T4[5]));
        E0w[2] = PMN(bu2, qu6);   E1w[2] = PMN(PMX(bu2, qu6), PMN(bt2, qt6));
        E0w[3] = PMN(bu3, qu7);   E1w[3] = PMN(PMX(bu3, qu7), PMN(bt3, qt7));
    }
    // ---- rowB: top3 (ascending) of T1 ----
    h2 B0w[4], B1w[4], B2w[4];
    {
        h2 c34u = PMN(T1[3], T1[4]), c34t = PMX(T1[3], T1[4]);
        h2 s2l = PMN(c34u, T1[2]);
        h2 s2m = PMX(c34u, PMN(c34t, T1[2]));
        h2 s2h = PMX(c34t, T1[2]);
        h2 s1h = PMX(s2h, T1[1]);
        h2 s1m = PMX(s2m, PMN(s2h, T1[1]));
        h2 s1l = PMX(s2l, PMN(s2m, T1[1]));
        h2 s0h = PMX(s1h, T1[0]);
        h2 s0m = PMX(s1m, PMN(s1h, T1[0]));
        h2 s0l = PMX(s1l, PMN(s1m, T1[0]));
        h2 p56u = PMN(T1[5], T1[6]), p56t = PMX(T1[5], T1[6]);
        h2 p7l = PMN(p56u, T1[7]);
        h2 p7m = PMX(p56u, PMN(p56t, T1[7]));
        h2 p7h = PMX(p56t, T1[7]);
        B0w[0] = s0l; B1w[0] = s0m; B2w[0] = s0h;
        { h2 x = T1[5];
          B2w[1] = PMX(s1h, x); B1w[1] = PMX(s1m, PMN(s1h, x)); B0w[1] = PMX(s1l, PMN(s1m, x)); }
        B2w[2] = PMX(s2h, p56t);
        B1w[2] = PMX(PMN(s2h, p56t), PMX(s2m, p56u));
        B0w[2] = PMX(PMX(PMN(s2h, p56u), PMN(s2m, p56t)), s2l);
        B2w[3] = PMX(p7h, c34t);
        B1w[3] = PMX(PMN(p7h, c34t), PMX(p7m, c34u));
        B0w[3] = PMX(PMX(PMN(p7h, c34u), PMN(p7m, c34t)), p7l);
    }
    // ---- rowD: bottom3 (ascending) of T3 ----
    h2 D0w[4], D1w[4], D2w[4];
    {
        h2 d34u = PMN(T3[3], T3[4]), d34t = PMX(T3[3], T3[4]);
        h2 u2l = PMN(d34u, T3[2]);
        h2 u2m = PMX(d34u, PMN(d34t, T3[2]));
        h2 u2h = PMX(d34t, T3[2]);
        h2 u1l = PMN(u2l, T3[1]);
        h2 u1m = PMN(u2m, PMX(u2l, T3[1]));
        h2 u1h = PMN(u2h, PMX(u2m, T3[1]));
        h2 u0l = PMN(u1l, T3[0]);
        h2 u0m = PMN(u1m, PMX(u1l, T3[0]));
        h2 u0h = PMN(u1h, PMX(u1m, T3[0]));
        h2 r56u = PMN(T3[5], T3[6]), r56t = PMX(T3[5], T3[6]);
        h2 r7l = PMN(r56u, T3[7]);
        h2 r7m = PMX(r56u, PMN(r56t, T3[7]));
        h2 r7h = PMX(r56t, T3[7]);
        D0w[0] = u0l; D1w[0] = u0m; D2w[0] = u0h;
        { h2 x = T3[5];
          D0w[1] = PMN(u1l, x); D1w[1] = PMN(u1m, PMX(u1l, x)); D2w[1] = PMN(u1h, PMX(u1m, x)); }
        D0w[2] = PMN(u2l, r56u);
        D1w[2] = PMN(PMX(u2l, r56u), PMN(u2m, r56t));
        D2w[2] = PMN(PMN(PMX(u2l, r56t), PMX(u2m, r56u)), u2h);
        D0w[3] = PMN(r7l, d34u);
        D1w[3] = PMN(PMX(r7l, d34u), PMN(r7m, d34t));
        D2w[3] = PMN(PMN(PMX(r7l, d34t), PMX(r7m, d34u)), r7h);
    }
    // ---- rowC: middle3 (ascending) of T2 ----
    h2 C0w[4], C1w[4], C2w[4];
    {
        h2 g34u = PMN(T2[3], T2[4]), g34t = PMX(T2[3], T2[4]);
        h2 g2l = PMN(g34u, T2[2]);
        h2 g2m = PMX(g34u, PMN(g34t, T2[2]));
        h2 g2h = PMX(g34t, T2[2]);
        // sorted4 of packs 1..4
        h2 s40 = PMN(g2l, T2[1]);
        h2 s41 = PMX(g2l, PMN(g2m, T2[1]));
        h2 s42 = PMX(g2m, PMN(g2h, T2[1]));
        h2 s43 = PMX(g2h, T2[1]);
        // W0 / W1: mid3 of sorted4 + inserted element
        C0w[0] = PMX(s40, PMN(s41, T2[0]));
        C1w[0] = PMX(s41, PMN(s42, T2[0]));
        C2w[0] = PMX(s42, PMN(s43, T2[0]));
        C0w[1] = PMX(s40, PMN(s41, T2[5]));
        C1w[1] = PMX(s41, PMN(s42, T2[5]));
        C2w[1] = PMX(s42, PMN(s43, T2[5]));
        // W2: merge sorted3(g2l,g2m,g2h) with sorted2(h56u,h56t);
        // 5-CE Batcher merge -> sorted (a0,a1,b0,b1,a2); mid3 = (a1,b0,b1)
        h2 h56u = PMN(T2[5], T2[6]), h56t = PMX(T2[5], T2[6]);
        { h2 a0 = g2l, a1 = g2m, a2 = g2h, b0 = h56u, b1 = h56t;
          PCE(a0, b0); PCE(b0, a2); PCE(a1, b1); PCE(a1, b0); PCE(b1, a2);
          C0w[2] = a1; C1w[2] = b0; C2w[2] = b1; }
        // W3: merge sorted3(5,6,7) with sorted2(3,4); same 5-CE merge
        h2 h7l = PMN(h56u, T2[7]);
        h2 h7m = PMX(h56u, PMN(h56t, T2[7]));
        h2 h7h = PMX(h56t, T2[7]);
        { h2 a0 = h7l, a1 = h7m, a2 = h7h, b0 = g34u, b1 = g34t;
          PCE(a0, b0); PCE(b0, a2); PCE(a1, b1); PCE(a1, b0); PCE(b1, a2);
          C0w[3] = a1; C1w[3] = b0; C2w[3] = b1; }
    }
    // ---- stage 2 per window ----
    h2 r0 = med13(A0w[0], A1w[0], B0w[0], B1w[0], B2w[0], C0w[0], C1w[0], C2w[0],
                  D0w[0], D1w[0], D2w[0], E0w[0], E1w[0]);
    h2 r1 = med13(A0w[1], A1w[1], B0w[1], B1w[1], B2w[1], C0w[1], C1w[1], C2w[1],
                  D0w[1], D1w[1], D2w[1], E0w[1], E1w[1]);
    h2 r2 = med13(A0w[2], A1w[2], B0w[2], B1w[2], B2w[2], C0w[2], C1w[2], C2w[2],
                  D0w[2], D1w[2], D2w[2], E0w[2], E1w[2]);
    h2 r3 = med13(A0w[3], A1w[3], B0w[3], B1w[3], B2w[3], C0w[3], C1w[3], C2w[3],
                  D0w[3], D1w[3], D2w[3], E0w[3], E1w[3]);
    f4a lo, hi;
    lo.x = (float)r0.x; lo.y = (float)r1.x; lo.z = (float)r2.x; lo.w = (float)r3.x;
    hi.x = (float)r0.y; hi.y = (float)r1.y; hi.z = (float)r2.y; hi.w = (float)r3.y;
    *(f4a*)outp = lo;
    *(f4a*)(outp + 4) = hi;
}

// row load: 12 floats (cols x0-2 .. x0+9) via 3 dwordx4 (8B-aligned base);
// pack[k] = (col x0-2+k, col x0+2+k) = (f[k], f[k+4])
__device__ __forceinline__ void loadrow_pack(const float* p, h2 out[8]) {
    f4u A = *(const f4u*)p;
    f4u B = *(const f4u*)(p + 4);
    f4u C = *(const f4u*)(p + 8);
    out[0] = __builtin_amdgcn_cvt_pkrtz(A.x, B.x);
    out[1] = __builtin_amdgcn_cvt_pkrtz(A.y, B.y);
    out[2] = __builtin_amdgcn_cvt_pkrtz(A.z, B.z);
    out[3] = __builtin_amdgcn_cvt_pkrtz(A.w, B.w);
    out[4] = __builtin_amdgcn_cvt_pkrtz(B.x, C.x);
    out[5] = __builtin_amdgcn_cvt_pkrtz(B.y, C.y);
    out[6] = __builtin_amdgcn_cvt_pkrtz(B.z, C.z);
    out[7] = __builtin_amdgcn_cvt_pkrtz(B.w, C.w);
}

__device__ __forceinline__ int refl(int z, int n) {
    z = (z < 0) ? -z : z;
    return (z >= n) ? 2 * n - 2 - z : z;
}

__global__ __launch_bounds__(256, 4) void median5x5_kernel(const float* __restrict__ in,
                                                           float* __restrict__ out) {
    int bc = blockIdx.y;
    const float* __restrict__ img  = in  + (size_t)bc * (H * W);
    float*       __restrict__ outc = out + (size_t)bc * (H * W);

    int x0, y0;
    h2 m1[8], m2[8], m3[8], m4[8];    // shared mid rows (y0-1..y0+2), packed
    h2 e0[8], e5[8];                  // edge rows (y0-2, y0+3), packed

    if ((int)blockIdx.x < IB) {
        int i = blockIdx.x * 256 + threadIdx.x;
        if (i >= TILES_I) return;
        int r  = i / QX_I;
        int qx = i - r * QX_I;
        x0 = 8 * (qx + 1);           // 8..496
        y0 = 2 * (r + 1);            // 2..508
        const float* base = img + (y0 - 2) * W + (x0 - 2);
        loadrow_pack(base + 1 * W, m1);
        loadrow_pack(base + 2 * W, m2);
        loadrow_pack(base + 3 * W, m3);
        loadrow_pack(base + 4 * W, m4);
        loadrow_pack(base + 0 * W, e0);
        loadrow_pack(base + 5 * W, e5);
    } else {
        int j = ((int)blockIdx.x - IB) * 256 + threadIdx.x;
        if (j >= EDGE_N) return;
        int qx, r;
        if (j < 512) { qx = (j & 1) ? 63 : 0; r = j >> 1; }
        else {
            int k2 = j - 512;
            if (k2 < QX_I) { r = 0;   qx = k2 + 1; }
            else           { r = 255; qx = k2 - (QX_I - 1); }
        }
        x0 = 8 * qx; y0 = 2 * r;
        int ry[6], rx[12];
        #pragma unroll
        for (int i2 = 0; i2 < 6; ++i2) ry[i2] = refl(y0 - 2 + i2, H);
        #pragma unroll
        for (int k = 0; k < 12; ++k) rx[k] = refl(x0 - 2 + k, W);
        h2* rows[6] = { e0, m1, m2, m3, m4, e5 };
        #pragma unroll
        for (int rr = 0; rr < 6; ++rr) {
            float tmp[12];
            #pragma unroll
            for (int k = 0; k < 12; ++k) tmp[k] = img[ry[rr] * W + rx[k]];
            #pragma unroll
            for (int k = 0; k < 8; ++k)
                rows[rr][k] = __builtin_amdgcn_cvt_pkrtz(tmp[k], tmp[k + 4]);
        }
    }

    // sorted-4 of shared mid rows, per packed column (mid rows die here)
    h2 q0[8], q1[8], q2[8], q3[8];
    #pragma unroll
    for (int k = 0; k < 8; ++k) {
        h2 a = m1[k], b = m2[k], c = m3[k], d = m4[k];
        h2 mn = PMN(a, b), mx = PMX(a, b);
        h2 l = PMN(mn, c), hh = PMX(mx, c);
        h2 m = PMX(mn, PMN(mx, c));
        q0[k] = PMN(l, d); q1[k] = IMD(m, l, d); q2[k] = IMD(hh, m, d); q3[k] = PMX(hh, d);
    }
    do_row(q0, q1, q2, q3, e0, outc + y0 * W + x0);
    do_row(q0, q1, q2, q3, e5, outc + (y0 + 1) * W + x0);
}

extern "C" void kernel_launch(void* const* d_in, const int* in_sizes, int n_in,
                              void* d_out, int out_size, void* d_ws, size_t ws_size,
                              hipStream_t stream) {
    const float* x = (const float*)d_in[0];
    float* out = (float*)d_out;
    int n_bc = in_sizes[0] / (H * W);       // 24
    dim3 grid(IB + EB, n_bc, 1);
    median5x5_kernel<<<grid, 256, 0, stream>>>(x, out);
}